// Round 1
// baseline (360.507 us; speedup 1.0000x reference)
//
#include <hip/hip_runtime.h>
#include <cstdint>
#include <climits>
#include <cstddef>

typedef unsigned long long u64;

#define B_ROWS 65536
#define BN_EPS 1e-5

// ---------------------------------------------------------------------------
// pack_kernel: binarize (src >= thresh) and bit-pack rows.
// One wave handles one 64-bit output word via __ballot (wave64).
// ---------------------------------------------------------------------------
template<int KW>
__global__ void pack_kernel(const float* __restrict__ src, u64* __restrict__ dst,
                            int rows, int cols, float thresh)
{
    const int lane   = threadIdx.x & 63;
    const int waveId = (blockIdx.x * blockDim.x + threadIdx.x) >> 6;
    const int nWaves = (gridDim.x * blockDim.x) >> 6;
    const int totalWords = rows * KW;
    for (int t = waveId; t < totalWords; t += nWaves) {
        const int row = t / KW;            // constant divisor (template)
        const int w   = t - row * KW;
        const int col = w * 64 + lane;
        bool pred = false;
        if (col < cols) pred = (src[(size_t)row * cols + col] >= thresh);
        u64 m = __ballot(pred);
        if (lane == 0) dst[t] = m;
    }
}

// ---------------------------------------------------------------------------
// init_stats: zero all per-layer stat accumulators (re-run every launch)
// ---------------------------------------------------------------------------
__global__ void init_stats(long long* gsum, long long* gsq, int* gmin, int* gmax,
                           double* colsum)
{
    int i = blockIdx.x * blockDim.x + threadIdx.x;
    if (i < 5 * 256) { gsum[i] = 0; gsq[i] = 0; gmin[i] = INT_MAX; gmax[i] = INT_MIN; }
    if (i < 10) colsum[i] = 0.0;
}

// ---------------------------------------------------------------------------
// matmul_stats: popcount GEMM, N=256 (thread <-> output column), 64 rows/block.
// Accumulates exact integer sum / sumsq / min / max per column via atomics.
// ---------------------------------------------------------------------------
template<int KW>
__global__ __launch_bounds__(256) void matmul_stats(const u64* __restrict__ abits,
    const u64* __restrict__ wbits,
    long long* gsum, long long* gsq, int* gmin, int* gmax, int K)
{
    __shared__ u64 sA[64 * KW];
    const int tid = threadIdx.x;
    u64 w[KW];
#pragma unroll
    for (int k = 0; k < KW; k++) w[k] = wbits[tid * KW + k];

    const size_t base = (size_t)blockIdx.x * 64 * KW;
    for (int i = tid; i < 64 * KW; i += 256) sA[i] = abits[base + i];
    __syncthreads();

    int lsum = 0, lsq = 0, lmin = INT_MAX, lmax = INT_MIN;
#pragma unroll 1
    for (int rr = 0; rr < 64; rr++) {
        int p = 0;
#pragma unroll
        for (int k = 0; k < KW; k++) p += __popcll(sA[rr * KW + k] ^ w[k]);
        const int v = K - 2 * p;
        lsum += v; lsq += v * v;
        lmin = min(lmin, v); lmax = max(lmax, v);
    }
    atomicAdd((u64*)&gsum[tid], (u64)(long long)lsum);
    atomicAdd((u64*)&gsq[tid],  (u64)(long long)lsq);
    atomicMin(&gmin[tid], lmin);
    atomicMax(&gmax[tid], lmax);
}

// ---------------------------------------------------------------------------
// finalize_bn: per-column integer binarization threshold from exact stats.
// z = gamma*(v-mean)*rsqrt(var+eps)+beta >= 0  <=>  sgn*v >= thr (v integer)
// ---------------------------------------------------------------------------
__global__ void finalize_bn(const long long* gsum, const long long* gsq,
                            const float* __restrict__ gamma, const float* __restrict__ beta,
                            int* sgn, int* thr)
{
    const int c = threadIdx.x;   // 256 columns
    const double mean = (double)gsum[c] / (double)B_ROWS;
    double var = (double)gsq[c] / (double)B_ROWS - mean * mean;
    if (var < 0.0) var = 0.0;
    const double rs    = 1.0 / sqrt(var + BN_EPS);
    const double scale = (double)gamma[c] * rs;
    const double bt    = (double)beta[c];
    int s, t;
    if (scale > 0.0)      { s = 1;  t = (int)ceil(mean - bt / scale); }
    else if (scale < 0.0) { s = -1; t = (int)(-floor(mean - bt / scale)); }
    else                  { s = 0;  t = (bt >= 0.0) ? INT_MIN : 1; }
    sgn[c] = s; thr[c] = t;
}

// ---------------------------------------------------------------------------
// matmul_pack: recompute popcount GEMM, apply integer threshold, ballot-pack
// next layer's activation bits (output N=256 -> 4 u64 words per row).
// ---------------------------------------------------------------------------
template<int KW>
__global__ __launch_bounds__(256) void matmul_pack(const u64* __restrict__ abits,
    const u64* __restrict__ wbits,
    const int* __restrict__ sgn, const int* __restrict__ thr,
    u64* __restrict__ obits, int K)
{
    __shared__ u64 sA[64 * KW];
    const int tid = threadIdx.x;
    u64 w[KW];
#pragma unroll
    for (int k = 0; k < KW; k++) w[k] = wbits[tid * KW + k];
    const int sg = sgn[tid];
    const int th = thr[tid];

    const size_t base = (size_t)blockIdx.x * 64 * KW;
    for (int i = tid; i < 64 * KW; i += 256) sA[i] = abits[base + i];
    __syncthreads();

    const int row0 = blockIdx.x * 64;
#pragma unroll 1
    for (int rr = 0; rr < 64; rr++) {
        int p = 0;
#pragma unroll
        for (int k = 0; k < KW; k++) p += __popcll(sA[rr * KW + k] ^ w[k]);
        const int v = K - 2 * p;
        const bool pred = (sg * v >= th);
        u64 m = __ballot(pred);
        if ((tid & 63) == 0) obits[(size_t)(row0 + rr) * 4 + (tid >> 6)] = m;
    }
}

// ---------------------------------------------------------------------------
// layer4_kernel: N=10 popcount GEMM; stores int16 outputs + exact stats.
// ---------------------------------------------------------------------------
__global__ __launch_bounds__(256) void layer4_kernel(const u64* __restrict__ abits,
    const u64* __restrict__ wbits, short* __restrict__ v4,
    long long* gsum, long long* gsq, int* gmin, int* gmax)
{
    __shared__ u64 sw[40];
    __shared__ int ssum[10], ssq[10], smin[10], smax[10];
    const int tid = threadIdx.x;
    if (tid < 40) sw[tid] = wbits[tid];
    if (tid < 10) { ssum[tid] = 0; ssq[tid] = 0; smin[tid] = INT_MAX; smax[tid] = INT_MIN; }
    __syncthreads();

    const int row = blockIdx.x * 256 + tid;
    const u64 a0 = abits[(size_t)row * 4 + 0];
    const u64 a1 = abits[(size_t)row * 4 + 1];
    const u64 a2 = abits[(size_t)row * 4 + 2];
    const u64 a3 = abits[(size_t)row * 4 + 3];

#pragma unroll
    for (int c = 0; c < 10; c++) {
        int p = __popcll(a0 ^ sw[c * 4 + 0]) + __popcll(a1 ^ sw[c * 4 + 1])
              + __popcll(a2 ^ sw[c * 4 + 2]) + __popcll(a3 ^ sw[c * 4 + 3]);
        const int v = 256 - 2 * p;
        v4[(size_t)row * 10 + c] = (short)v;
        int s = v, q = v * v, mn = v, mx = v;
        for (int off = 32; off > 0; off >>= 1) {
            s += __shfl_xor(s, off);
            q += __shfl_xor(q, off);
            mn = min(mn, __shfl_xor(mn, off));
            mx = max(mx, __shfl_xor(mx, off));
        }
        if ((tid & 63) == 0) {
            atomicAdd(&ssum[c], s); atomicAdd(&ssq[c], q);
            atomicMin(&smin[c], mn); atomicMax(&smax[c], mx);
        }
    }
    __syncthreads();
    if (tid < 10) {
        atomicAdd((u64*)&gsum[tid], (u64)(long long)ssum[tid]);
        atomicAdd((u64*)&gsq[tid],  (u64)(long long)ssq[tid]);
        atomicMin(&gmin[tid], smin[tid]);
        atomicMax(&gmax[tid], smax[tid]);
    }
}

// ---------------------------------------------------------------------------
// finalize4: BN affine for layer 4 (z = zs*v + bias) and shift by column max
// of z (derived exactly from integer min/max since z is monotone in v).
// ---------------------------------------------------------------------------
__global__ void finalize4(const long long* gsum, const long long* gsq,
                          const int* gmin, const int* gmax,
                          const float* __restrict__ gamma, const float* __restrict__ beta,
                          double* zs, double* zb)
{
    const int c = threadIdx.x;
    if (c >= 10) return;
    const double mean = (double)gsum[c] / (double)B_ROWS;
    double var = (double)gsq[c] / (double)B_ROWS - mean * mean;
    if (var < 0.0) var = 0.0;
    const double rs    = 1.0 / sqrt(var + BN_EPS);
    const double scale = (double)gamma[c] * rs;
    const double bias  = (double)beta[c] - mean * scale;
    const double z1 = scale * (double)gmin[c] + bias;
    const double z2 = scale * (double)gmax[c] + bias;
    const double zmax = fmax(z1, z2);
    zs[c] = scale;
    zb[c] = bias - zmax;
}

// ---------------------------------------------------------------------------
// colsum_kernel: per-column sum of exp(z - zmax) in double (10 cols).
// ---------------------------------------------------------------------------
__global__ __launch_bounds__(256) void colsum_kernel(const short* __restrict__ v4,
    const double* __restrict__ zs, const double* __restrict__ zb, double* colsum)
{
    __shared__ double sred[256];
    const int c     = blockIdx.x % 10;
    const int chunk = blockIdx.x / 10;     // 64 chunks x 1024 rows
    const int tid   = threadIdx.x;
    const double scale = zs[c], b = zb[c];
    double acc = 0.0;
    const int r0 = chunk * 1024;
#pragma unroll
    for (int i = 0; i < 4; i++) {
        const int r = r0 + i * 256 + tid;
        const int v = v4[(size_t)r * 10 + c];
        acc += exp(scale * (double)v + b);
    }
    sred[tid] = acc; __syncthreads();
    for (int s = 128; s > 0; s >>= 1) {
        if (tid < s) sred[tid] += sred[tid + s];
        __syncthreads();
    }
    if (tid == 0) atomicAdd(&colsum[c], sred[0]);
}

// ---------------------------------------------------------------------------
// out_kernel: out = exp(z - zmax) / colsum  (recompute exp; coalesced write)
// ---------------------------------------------------------------------------
__global__ void out_kernel(const short* __restrict__ v4, const double* __restrict__ zs,
    const double* __restrict__ zb, const double* __restrict__ colsum,
    float* __restrict__ out)
{
    const int idx = blockIdx.x * blockDim.x + threadIdx.x;
    if (idx >= B_ROWS * 10) return;
    const int c = idx % 10;
    const int v = v4[idx];
    const double e = exp(zs[c] * (double)v + zb[c]);
    out[idx] = (float)(e / colsum[c]);
}

// ---------------------------------------------------------------------------
extern "C" void kernel_launch(void* const* d_in, const int* in_sizes, int n_in,
                              void* d_out, int out_size, void* d_ws, size_t ws_size,
                              hipStream_t stream)
{
    const float* x = (const float*)d_in[0];
    const float* w[5]; const float* gamma[5]; const float* beta[5];
    for (int k = 0; k < 5; k++) {
        w[k]     = (const float*)d_in[1 + 3 * k];
        gamma[k] = (const float*)d_in[2 + 3 * k];
        beta[k]  = (const float*)d_in[3 + 3 * k];
    }

    char* p = (char*)d_ws;
    auto alloc = [&](size_t bytes) -> char* {
        char* r = p;
        p += (bytes + 255) & ~(size_t)255;
        return r;
    };
    u64*       bitsx  = (u64*)alloc(65536ull * 13 * 8);
    u64*       bitsA  = (u64*)alloc(65536ull * 4 * 8);
    u64*       bitsB  = (u64*)alloc(65536ull * 4 * 8);
    u64*       wb     = (u64*)alloc(256ull * 13 * 8);
    long long* gsum   = (long long*)alloc(5 * 256 * 8);
    long long* gsq    = (long long*)alloc(5 * 256 * 8);
    int*       gmin   = (int*)alloc(5 * 256 * 4);
    int*       gmax   = (int*)alloc(5 * 256 * 4);
    int*       sgn    = (int*)alloc(4 * 256 * 4);
    int*       thr    = (int*)alloc(4 * 256 * 4);
    double*    zs     = (double*)alloc(10 * 8);
    double*    zb     = (double*)alloc(10 * 8);
    double*    colsum = (double*)alloc(10 * 8);
    short*     v4     = (short*)alloc(65536ull * 10 * 2);
    float*     out    = (float*)d_out;

    init_stats<<<5, 256, 0, stream>>>(gsum, gsq, gmin, gmax, colsum);

    // binarize(x - 0.5) -> bits  (x >= 0.5)
    pack_kernel<13><<<2048, 256, 0, stream>>>(x, bitsx, 65536, 784, 0.5f);

    // ---- layer 0 (K=784, 13 words) ----
    pack_kernel<13><<<16, 256, 0, stream>>>(w[0], wb, 256, 784, 0.0f);
    matmul_stats<13><<<1024, 256, 0, stream>>>(bitsx, wb, gsum, gsq, gmin, gmax, 784);
    finalize_bn<<<1, 256, 0, stream>>>(gsum, gsq, gamma[0], beta[0], sgn, thr);
    matmul_pack<13><<<1024, 256, 0, stream>>>(bitsx, wb, sgn, thr, bitsA, 784);

    // ---- layers 1..3 (K=256, 4 words) ----
    u64* src = bitsA; u64* dst = bitsB;
    for (int k = 1; k < 4; k++) {
        pack_kernel<4><<<8, 256, 0, stream>>>(w[k], wb, 256, 256, 0.0f);
        matmul_stats<4><<<1024, 256, 0, stream>>>(src, wb, gsum + k * 256, gsq + k * 256,
                                                  gmin + k * 256, gmax + k * 256, 256);
        finalize_bn<<<1, 256, 0, stream>>>(gsum + k * 256, gsq + k * 256, gamma[k], beta[k],
                                           sgn + k * 256, thr + k * 256);
        matmul_pack<4><<<1024, 256, 0, stream>>>(src, wb, sgn + k * 256, thr + k * 256, dst, 256);
        u64* t = src; src = dst; dst = t;
    }

    // ---- layer 4 (K=256 -> 10 cols) ----
    pack_kernel<4><<<2, 256, 0, stream>>>(w[4], wb, 10, 256, 0.0f);
    layer4_kernel<<<256, 256, 0, stream>>>(src, wb, v4, gsum + 4 * 256, gsq + 4 * 256,
                                           gmin + 4 * 256, gmax + 4 * 256);
    finalize4<<<1, 64, 0, stream>>>(gsum + 4 * 256, gsq + 4 * 256, gmin + 4 * 256, gmax + 4 * 256,
                                    gamma[4], beta[4], zs, zb);

    // ---- softmax over batch axis ----
    colsum_kernel<<<640, 256, 0, stream>>>(v4, zs, zb, colsum);
    out_kernel<<<2560, 256, 0, stream>>>(v4, zs, zb, colsum, out);
}

// Round 2
// 349.255 us; speedup vs baseline: 1.0322x; 1.0322x over previous
//
#include <hip/hip_runtime.h>
#include <cstdint>
#include <climits>
#include <cstddef>

typedef unsigned long long u64;

#define B_ROWS 65536
#define BN_EPS 1e-5

// ---------------------------------------------------------------------------
// pack_kernel: binarize (src >= thresh), bit-pack rows, ROW-MAJOR bit order.
// One wave per 64-bit word via __ballot. Used for x (and layer-0 weights in
// prep). 205 MB read for x -> HBM-bound.
// ---------------------------------------------------------------------------
template<int KW>
__global__ __launch_bounds__(256) void pack_kernel(const float* __restrict__ src,
    u64* __restrict__ dst, int rows, int cols, float thresh)
{
    const int lane   = threadIdx.x & 63;
    const int waveId = (blockIdx.x * blockDim.x + threadIdx.x) >> 6;
    const int nWaves = (gridDim.x * blockDim.x) >> 6;
    const int totalWords = rows * KW;
    for (int t = waveId; t < totalWords; t += nWaves) {
        const int row = t / KW;            // constant divisor (template)
        const int w   = t - row * KW;
        const int col = w * 64 + lane;
        bool pred = false;
        if (col < cols) pred = (src[(size_t)row * cols + col] >= thresh);
        u64 m = __ballot(pred);
        if (lane == 0) dst[t] = m;
    }
}

// ---------------------------------------------------------------------------
// prep_kernel: ONE launch doing (A) layer-0 weight pack row-major 13 words,
// (B) layers 1-4 weight pack in INTERLEAVED order (word e bit i = col 4i+e,
// matching packv's float4/ballot order), (C) zero all stat accumulators.
// ---------------------------------------------------------------------------
__global__ __launch_bounds__(256) void prep_kernel(
    const float* __restrict__ w0, const float* __restrict__ w1,
    const float* __restrict__ w2, const float* __restrict__ w3,
    const float* __restrict__ w4,
    u64* __restrict__ wb0, u64* __restrict__ wbI,
    long long* gsum, long long* gsq, int* gmin, int* gmax, double* colsum)
{
    const int lane = threadIdx.x & 63;
    const int wv   = threadIdx.x >> 6;
    const int b    = blockIdx.x;

    if (b < 64) {
        // ---- section A: w0 (256 x 784) row-major pack, wave per row ----
        const int row = b * 4 + wv;
#pragma unroll
        for (int w = 0; w < 13; w++) {
            const int col = w * 64 + lane;
            bool pred = false;
            if (col < 784) pred = (w0[(size_t)row * 784 + col] >= 0.0f);
            u64 m = __ballot(pred);
            if (lane == 0) wb0[row * 13 + w] = m;
        }
    } else if (b < 259) {
        // ---- section B: w1..w4 interleaved pack, wave per row ----
        const int rowI = (b - 64) * 4 + wv;      // 0..777
        if (rowI < 778) {
            const float* src; int srcRow;
            if      (rowI < 256) { src = w1; srcRow = rowI; }
            else if (rowI < 512) { src = w2; srcRow = rowI - 256; }
            else if (rowI < 768) { src = w3; srcRow = rowI - 512; }
            else                 { src = w4; srcRow = rowI - 768; }
            const float4 f = *(const float4*)(src + (size_t)srcRow * 256 + 4 * lane);
            u64 b0 = __ballot(f.x >= 0.0f);
            u64 b1 = __ballot(f.y >= 0.0f);
            u64 b2 = __ballot(f.z >= 0.0f);
            u64 b3 = __ballot(f.w >= 0.0f);
            if (lane == 0) {
                ulonglong2* o = (ulonglong2*)(wbI + (size_t)rowI * 4);
                o[0] = make_ulonglong2(b0, b1);
                o[1] = make_ulonglong2(b2, b3);
            }
        }
    } else {
        // ---- section C: init stats ----
        for (int i = threadIdx.x; i < 5 * 256; i += 256) {
            gsum[i] = 0; gsq[i] = 0; gmin[i] = INT_MAX; gmax[i] = INT_MIN;
        }
        if (threadIdx.x < 10) colsum[threadIdx.x] = 0.0;
    }
}

// ---------------------------------------------------------------------------
// gemm_stats: single-pass popcount GEMM. thread <-> output column (256 threads),
// A-row words are wave-uniform loads (s_load candidates), weights in VGPRs.
// Stores v (int16) and accumulates exact per-column sum / sumsq in registers,
// one atomic pair per thread at the end. No LDS, no cross-lane reduce.
// ---------------------------------------------------------------------------
template<int KW, int RPB>
__global__ __launch_bounds__(256) void gemm_stats(const u64* __restrict__ abits,
    const u64* __restrict__ wbits, short* __restrict__ vout,
    long long* gsum, long long* gsq, int K)
{
    const int c = threadIdx.x;
    u64 w[KW];
#pragma unroll
    for (int k = 0; k < KW; k++) w[k] = wbits[(size_t)c * KW + k];

    const int r0 = blockIdx.x * RPB;
    int isum = 0;
    int isq  = 0;
#pragma unroll 2
    for (int r = r0; r < r0 + RPB; ++r) {
        const u64* arow = abits + (size_t)r * KW;   // uniform address
        int p = 0;
#pragma unroll
        for (int k = 0; k < KW; k++) p += __popcll(arow[k] ^ w[k]);
        const int v = K - 2 * p;
        vout[((size_t)r << 8) + c] = (short)v;
        isum += v; isq += v * v;
    }
    atomicAdd((u64*)&gsum[c], (u64)(long long)isum);
    atomicAdd((u64*)&gsq[c],  (u64)(long long)isq);
}

// ---------------------------------------------------------------------------
// finalize_bn: per-column integer binarization threshold from exact stats.
// ---------------------------------------------------------------------------
__global__ void finalize_bn(const long long* gsum, const long long* gsq,
                            const float* __restrict__ gamma, const float* __restrict__ beta,
                            int* sgn, int* thr)
{
    const int c = threadIdx.x;   // 256 columns
    const double mean = (double)gsum[c] / (double)B_ROWS;
    double var = (double)gsq[c] / (double)B_ROWS - mean * mean;
    if (var < 0.0) var = 0.0;
    const double rs    = 1.0 / sqrt(var + BN_EPS);
    const double scale = (double)gamma[c] * rs;
    const double bt    = (double)beta[c];
    int s, t;
    if (scale > 0.0)      { s = 1;  t = (int)ceil(mean - bt / scale); }
    else if (scale < 0.0) { s = -1; t = (int)(-floor(mean - bt / scale)); }
    else                  { s = 0;  t = (bt >= 0.0) ? INT_MIN : 1; }
    sgn[c] = s; thr[c] = t;
}

// ---------------------------------------------------------------------------
// packv_kernel: threshold stored v and bit-pack in INTERLEAVED order.
// One wave covers a full 256-col row: lane reads short4 (cols 4l..4l+3),
// 4 ballots -> 4 words. Fully coalesced 512 B/row reads.
// ---------------------------------------------------------------------------
__global__ __launch_bounds__(256) void packv_kernel(const short* __restrict__ v,
    const int* __restrict__ sgn, const int* __restrict__ thr,
    u64* __restrict__ obits, int rowsPerWave)
{
    const int lane = threadIdx.x & 63;
    const int wv   = threadIdx.x >> 6;
    const int waveId = blockIdx.x * 4 + wv;
    int sg[4], th[4];
#pragma unroll
    for (int e = 0; e < 4; e++) { sg[e] = sgn[4 * lane + e]; th[e] = thr[4 * lane + e]; }
    const int r0 = waveId * rowsPerWave;
    for (int r = r0; r < r0 + rowsPerWave; ++r) {
        const short4 vv = *(const short4*)(v + ((size_t)r << 8) + 4 * lane);
        u64 b0 = __ballot(sg[0] * (int)vv.x >= th[0]);
        u64 b1 = __ballot(sg[1] * (int)vv.y >= th[1]);
        u64 b2 = __ballot(sg[2] * (int)vv.z >= th[2]);
        u64 b3 = __ballot(sg[3] * (int)vv.w >= th[3]);
        if (lane == 0) {
            ulonglong2* o = (ulonglong2*)(obits + ((size_t)r << 2));
            o[0] = make_ulonglong2(b0, b1);
            o[1] = make_ulonglong2(b2, b3);
        }
    }
}

// ---------------------------------------------------------------------------
// layer4_kernel: N=10 popcount GEMM; stores int16 outputs + exact stats.
// ---------------------------------------------------------------------------
__global__ __launch_bounds__(256) void layer4_kernel(const u64* __restrict__ abits,
    const u64* __restrict__ wbits, short* __restrict__ v4,
    long long* gsum, long long* gsq, int* gmin, int* gmax)
{
    __shared__ u64 sw[40];
    __shared__ int ssum[10], ssq[10], smin[10], smax[10];
    const int tid = threadIdx.x;
    if (tid < 40) sw[tid] = wbits[tid];
    if (tid < 10) { ssum[tid] = 0; ssq[tid] = 0; smin[tid] = INT_MAX; smax[tid] = INT_MIN; }
    __syncthreads();

    const int row = blockIdx.x * 256 + tid;
    const u64 a0 = abits[(size_t)row * 4 + 0];
    const u64 a1 = abits[(size_t)row * 4 + 1];
    const u64 a2 = abits[(size_t)row * 4 + 2];
    const u64 a3 = abits[(size_t)row * 4 + 3];

#pragma unroll
    for (int c = 0; c < 10; c++) {
        int p = __popcll(a0 ^ sw[c * 4 + 0]) + __popcll(a1 ^ sw[c * 4 + 1])
              + __popcll(a2 ^ sw[c * 4 + 2]) + __popcll(a3 ^ sw[c * 4 + 3]);
        const int v = 256 - 2 * p;
        v4[(size_t)row * 10 + c] = (short)v;
        int s = v, q = v * v, mn = v, mx = v;
        for (int off = 32; off > 0; off >>= 1) {
            s += __shfl_xor(s, off);
            q += __shfl_xor(q, off);
            mn = min(mn, __shfl_xor(mn, off));
            mx = max(mx, __shfl_xor(mx, off));
        }
        if ((tid & 63) == 0) {
            atomicAdd(&ssum[c], s); atomicAdd(&ssq[c], q);
            atomicMin(&smin[c], mn); atomicMax(&smax[c], mx);
        }
    }
    __syncthreads();
    if (tid < 10) {
        atomicAdd((u64*)&gsum[tid], (u64)(long long)ssum[tid]);
        atomicAdd((u64*)&gsq[tid],  (u64)(long long)ssq[tid]);
        atomicMin(&gmin[tid], smin[tid]);
        atomicMax(&gmax[tid], smax[tid]);
    }
}

// ---------------------------------------------------------------------------
// finalize4: BN affine for layer 4 and exact column-max shift.
// ---------------------------------------------------------------------------
__global__ void finalize4(const long long* gsum, const long long* gsq,
                          const int* gmin, const int* gmax,
                          const float* __restrict__ gamma, const float* __restrict__ beta,
                          double* zs, double* zb)
{
    const int c = threadIdx.x;
    if (c >= 10) return;
    const double mean = (double)gsum[c] / (double)B_ROWS;
    double var = (double)gsq[c] / (double)B_ROWS - mean * mean;
    if (var < 0.0) var = 0.0;
    const double rs    = 1.0 / sqrt(var + BN_EPS);
    const double scale = (double)gamma[c] * rs;
    const double bias  = (double)beta[c] - mean * scale;
    const double z1 = scale * (double)gmin[c] + bias;
    const double z2 = scale * (double)gmax[c] + bias;
    const double zmax = fmax(z1, z2);
    zs[c] = scale;
    zb[c] = bias - zmax;
}

// ---------------------------------------------------------------------------
// colsum_kernel: per-column sum of exp(z - zmax) in double (10 cols).
// ---------------------------------------------------------------------------
__global__ __launch_bounds__(256) void colsum_kernel(const short* __restrict__ v4,
    const double* __restrict__ zs, const double* __restrict__ zb, double* colsum)
{
    __shared__ double sred[256];
    const int c     = blockIdx.x % 10;
    const int chunk = blockIdx.x / 10;     // 64 chunks x 1024 rows
    const int tid   = threadIdx.x;
    const double scale = zs[c], b = zb[c];
    double acc = 0.0;
    const int r0 = chunk * 1024;
#pragma unroll
    for (int i = 0; i < 4; i++) {
        const int r = r0 + i * 256 + tid;
        const int v = v4[(size_t)r * 10 + c];
        acc += exp(scale * (double)v + b);
    }
    sred[tid] = acc; __syncthreads();
    for (int s = 128; s > 0; s >>= 1) {
        if (tid < s) sred[tid] += sred[tid + s];
        __syncthreads();
    }
    if (tid == 0) atomicAdd(&colsum[c], sred[0]);
}

// ---------------------------------------------------------------------------
// out_kernel: out = exp(z - zmax) / colsum
// ---------------------------------------------------------------------------
__global__ void out_kernel(const short* __restrict__ v4, const double* __restrict__ zs,
    const double* __restrict__ zb, const double* __restrict__ colsum,
    float* __restrict__ out)
{
    const int idx = blockIdx.x * blockDim.x + threadIdx.x;
    if (idx >= B_ROWS * 10) return;
    const int c = idx % 10;
    const int v = v4[idx];
    const double e = exp(zs[c] * (double)v + zb[c]);
    out[idx] = (float)(e / colsum[c]);
}

// ---------------------------------------------------------------------------
extern "C" void kernel_launch(void* const* d_in, const int* in_sizes, int n_in,
                              void* d_out, int out_size, void* d_ws, size_t ws_size,
                              hipStream_t stream)
{
    const float* x = (const float*)d_in[0];
    const float* w[5]; const float* gamma[5]; const float* beta[5];
    for (int k = 0; k < 5; k++) {
        w[k]     = (const float*)d_in[1 + 3 * k];
        gamma[k] = (const float*)d_in[2 + 3 * k];
        beta[k]  = (const float*)d_in[3 + 3 * k];
    }

    char* p = (char*)d_ws;
    auto alloc = [&](size_t bytes) -> char* {
        char* r = p;
        p += (bytes + 255) & ~(size_t)255;
        return r;
    };
    u64*       bitsx  = (u64*)alloc(65536ull * 13 * 8);
    u64*       bitsA  = (u64*)alloc(65536ull * 4 * 8);
    u64*       bitsB  = (u64*)alloc(65536ull * 4 * 8);
    u64*       wb0    = (u64*)alloc(256ull * 13 * 8);
    u64*       wbI    = (u64*)alloc(778ull * 4 * 8);
    short*     v      = (short*)alloc(65536ull * 256 * 2);
    long long* gsum   = (long long*)alloc(5 * 256 * 8);
    long long* gsq    = (long long*)alloc(5 * 256 * 8);
    int*       gmin   = (int*)alloc(5 * 256 * 4);
    int*       gmax   = (int*)alloc(5 * 256 * 4);
    int*       sgn    = (int*)alloc(256 * 4);
    int*       thr    = (int*)alloc(256 * 4);
    double*    zs     = (double*)alloc(10 * 8);
    double*    zb     = (double*)alloc(10 * 8);
    double*    colsum = (double*)alloc(10 * 8);
    short*     v4     = (short*)alloc(65536ull * 10 * 2);
    float*     out    = (float*)d_out;

    // weight packing (w0 row-major; w1..w4 interleaved) + stat init, one launch
    prep_kernel<<<260, 256, 0, stream>>>(w[0], w[1], w[2], w[3], w[4],
                                         wb0, wbI, gsum, gsq, gmin, gmax, colsum);

    // binarize(x - 0.5) -> bits (x >= 0.5), row-major order
    pack_kernel<13><<<2048, 256, 0, stream>>>(x, bitsx, 65536, 784, 0.5f);

    // ---- layer 0 (K=784, 13 words) ----
    gemm_stats<13, 128><<<512, 256, 0, stream>>>(bitsx, wb0, v, gsum, gsq, 784);
    finalize_bn<<<1, 256, 0, stream>>>(gsum, gsq, gamma[0], beta[0], sgn, thr);
    packv_kernel<<<256, 256, 0, stream>>>(v, sgn, thr, bitsA, 64);

    // ---- layers 1..3 (K=256, 4 words, interleaved order) ----
    u64* src = bitsA; u64* dst = bitsB;
    for (int k = 1; k < 4; k++) {
        gemm_stats<4, 128><<<512, 256, 0, stream>>>(src, wbI + (size_t)(k - 1) * 1024, v,
                                                    gsum + k * 256, gsq + k * 256, 256);
        finalize_bn<<<1, 256, 0, stream>>>(gsum + k * 256, gsq + k * 256, gamma[k], beta[k],
                                           sgn, thr);
        packv_kernel<<<256, 256, 0, stream>>>(v, sgn, thr, dst, 64);
        u64* t = src; src = dst; dst = t;
    }

    // ---- layer 4 (K=256 -> 10 cols) ----
    layer4_kernel<<<256, 256, 0, stream>>>(src, wbI + 3072, v4, gsum + 4 * 256, gsq + 4 * 256,
                                           gmin + 4 * 256, gmax + 4 * 256);
    finalize4<<<1, 64, 0, stream>>>(gsum + 4 * 256, gsq + 4 * 256, gmin + 4 * 256, gmax + 4 * 256,
                                    gamma[4], beta[4], zs, zb);

    // ---- softmax over batch axis ----
    colsum_kernel<<<640, 256, 0, stream>>>(v4, zs, zb, colsum);
    out_kernel<<<2560, 256, 0, stream>>>(v4, zs, zb, colsum, out);
}